// Round 1
// baseline (380.380 us; speedup 1.0000x reference)
//
#include <hip/hip_runtime.h>
#include <cstdint>

typedef unsigned short ushort_t;
typedef __attribute__((ext_vector_type(8))) short short8;
typedef __attribute__((ext_vector_type(4))) float f32x4;

#define B_ 2
#define T_ 2048
#define D_ 1024
#define H_ 16
#define DH_ 64

__device__ inline unsigned short f2bf(float f) {
  unsigned int u = __float_as_uint(f);
  u += 0x7FFF + ((u >> 16) & 1);   // round-to-nearest-even
  return (unsigned short)(u >> 16);
}

__device__ inline f32x4 mfma16(short8 a, short8 b, f32x4 c) {
  return __builtin_amdgcn_mfma_f32_16x16x32_bf16(a, b, c, 0, 0, 0);
}

// async global->LDS, 16B per lane. LDS dest = wave-uniform base + lane*16.
__device__ inline void gload16(const void* g, void* l) {
  __builtin_amdgcn_global_load_lds(
      (const __attribute__((address_space(1))) unsigned int*)(uintptr_t)g,
      (__attribute__((address_space(3))) unsigned int*)(uint32_t)(uintptr_t)l,
      16, 0, 0);
}

// ---------------- fp32 -> bf16 elementwise ----------------
__global__ void k_cvt(const float* __restrict__ in, ushort_t* __restrict__ out, int n4) {
  int i = blockIdx.x * blockDim.x + threadIdx.x;
  if (i >= n4) return;
  float4 v = ((const float4*)in)[i];
  ushort4 o;
  o.x = f2bf(v.x); o.y = f2bf(v.y); o.z = f2bf(v.z); o.w = f2bf(v.w);
  ((ushort4*)out)[i] = o;
}

// ------------- fp32 [R][C] -> bf16 [C][R] (transpose+convert) -------------
__global__ void k_tcvt(const float* __restrict__ in, ushort_t* __restrict__ out,
                       int R, int C) {
  __shared__ float tile[32][33];
  int c0 = blockIdx.x * 32, r0 = blockIdx.y * 32;
  int tx = threadIdx.x, ty = threadIdx.y;   // 32 x 8
#pragma unroll
  for (int i = 0; i < 32; i += 8)
    tile[ty + i][tx] = in[(size_t)(r0 + ty + i) * C + c0 + tx];
  __syncthreads();
#pragma unroll
  for (int i = 0; i < 32; i += 8)
    out[(size_t)(c0 + ty + i) * R + r0 + tx] = f2bf(tile[tx][ty + i]);
}

// ------------- transpose V slice of qkv into vt[bh][d][t] (bf16) -------------
__global__ void k_tv(const ushort_t* __restrict__ qkv, ushort_t* __restrict__ vt) {
  __shared__ ushort_t tile[32][33];
  int bh = blockIdx.z;
  int b = bh >> 4, hh = bh & 15;
  int t0 = blockIdx.x * 32, d0 = blockIdx.y * 32;
  int tx = threadIdx.x, ty = threadIdx.y;   // 32 x 8
#pragma unroll
  for (int i = 0; i < 32; i += 8)
    tile[ty + i][tx] =
        qkv[(size_t)(b * T_ + t0 + ty + i) * (3 * D_) + 2 * D_ + hh * DH_ + d0 + tx];
  __syncthreads();
#pragma unroll
  for (int i = 0; i < 32; i += 8)
    vt[(size_t)(bh * DH_ + d0 + ty + i) * T_ + t0 + tx] = tile[tx][ty + i];
}

// ------------- bf16 GEMM, C = A[M][K] * Bt[N][K]^T  (m97-style 128^2) -------------
template <int OUTF>   // 1: fp32 out, 0: bf16 out
__global__ __launch_bounds__(256, 2) void k_gemm_bt(
    const ushort_t* __restrict__ A, const ushort_t* __restrict__ Bt,
    void* __restrict__ C, int M, int N, int K) {
  __shared__ __align__(16) ushort_t As[128 * 32];
  __shared__ __align__(16) ushort_t Bs[128 * 32];
  const int tid = threadIdx.x;
  const int w = tid >> 6, l = tid & 63;
  const int bm = blockIdx.y, bn = blockIdx.x;
  const int wm = w >> 1, wn = w & 1;

  const f32x4 fz = {0.f, 0.f, 0.f, 0.f};
  f32x4 acc[4][4];
#pragma unroll
  for (int i = 0; i < 4; ++i)
#pragma unroll
    for (int j = 0; j < 4; ++j) acc[i][j] = fz;

  const int r_a = l >> 2;          // row-within-16 for staging
  const int cb = (l & 3) * 16;     // byte col within 64B row
  const int lrow = l & 15;
  const int lk16 = (l >> 4) * 16;  // k-slot byte offset

  for (int k0 = 0; k0 < K; k0 += 32) {
    __syncthreads();
#pragma unroll
    for (int c = 0; c < 2; ++c) {
      int row = (w * 2 + c) * 16 + r_a;
      gload16((const char*)A + ((size_t)(bm * 128 + row) * K + k0) * 2 + cb,
              (char*)As + row * 64 + cb);
      gload16((const char*)Bt + ((size_t)(bn * 128 + row) * K + k0) * 2 + cb,
              (char*)Bs + row * 64 + cb);
    }
    __syncthreads();
    short8 af[4], bv[4];
#pragma unroll
    for (int mt = 0; mt < 4; ++mt)
      af[mt] = *(const short8*)((const char*)As + (wm * 64 + mt * 16 + lrow) * 64 + lk16);
#pragma unroll
    for (int nt = 0; nt < 4; ++nt)
      bv[nt] = *(const short8*)((const char*)Bs + (wn * 64 + nt * 16 + lrow) * 64 + lk16);
#pragma unroll
    for (int mt = 0; mt < 4; ++mt)
#pragma unroll
      for (int nt = 0; nt < 4; ++nt)
        acc[mt][nt] = mfma16(af[mt], bv[nt], acc[mt][nt]);
  }

  const int rg = (l >> 4) * 4;
#pragma unroll
  for (int mt = 0; mt < 4; ++mt)
#pragma unroll
    for (int nt = 0; nt < 4; ++nt) {
      size_t col = (size_t)bn * 128 + wn * 64 + nt * 16 + lrow;
#pragma unroll
      for (int r = 0; r < 4; ++r) {
        size_t rowi = (size_t)bm * 128 + wm * 64 + mt * 16 + rg + r;
        if (OUTF)
          ((float*)C)[rowi * N + col] = acc[mt][nt][r];
        else
          ((ushort_t*)C)[rowi * N + col] = f2bf(acc[mt][nt][r]);
      }
    }
}

// ------------- causal flash attention, 1 block = 64 q rows of one (b,h) -------------
__global__ __launch_bounds__(256) void k_attn(
    const ushort_t* __restrict__ qkv, const ushort_t* __restrict__ vt,
    ushort_t* __restrict__ ctx) {
  __shared__ __align__(16) ushort_t plds[4][16][40];   // P tile per wave, padded
  const int tid = threadIdx.x;
  const int w = tid >> 6, l = tid & 63;
  const int qt = blockIdx.x;
  const int bh = blockIdx.y;
  const int b = bh >> 4, hh = bh & 15;
  const int qr0 = qt * 64 + w * 16;
  const int lrow = l & 15, lg = l >> 4;

  // Q fragments (A operand, k = head dim)
  short8 aq0, aq1;
  {
    const ushort_t* qbase =
        qkv + (size_t)(b * T_ + qr0 + lrow) * (3 * D_) + hh * DH_ + lg * 8;
    aq0 = *(const short8*)(qbase);
    aq1 = *(const short8*)(qbase + 32);
  }

  const f32x4 fz = {0.f, 0.f, 0.f, 0.f};
  f32x4 o[4];
#pragma unroll
  for (int nt = 0; nt < 4; ++nt) o[nt] = fz;
  float mrow[4] = {-1e30f, -1e30f, -1e30f, -1e30f};
  float lsum[4] = {0.f, 0.f, 0.f, 0.f};

  const int ntiles = qr0 / 32 + 1;
  for (int t = 0; t < ntiles; ++t) {
    const int kv0 = t * 32;
    // S = Q K^T (two 16-col halves), fp32 acc
    f32x4 s[2];
#pragma unroll
    for (int nh = 0; nh < 2; ++nh) {
      const ushort_t* kbase =
          qkv + (size_t)(b * T_ + kv0 + nh * 16 + lrow) * (3 * D_) + D_ + hh * DH_ + lg * 8;
      short8 bk0 = *(const short8*)(kbase);
      short8 bk1 = *(const short8*)(kbase + 32);
      f32x4 z = mfma16(aq0, bk0, fz);
      s[nh] = mfma16(aq1, bk1, z);
    }
    // scale + causal mask + tile row-max
    float tm[4];
#pragma unroll
    for (int r = 0; r < 4; ++r) {
      int row = qr0 + lg * 4 + r;
#pragma unroll
      for (int nh = 0; nh < 2; ++nh) {
        int col = kv0 + nh * 16 + lrow;
        float v = s[nh][r] * 0.125f;
        s[nh][r] = (col <= row) ? v : -1e30f;
      }
      tm[r] = fmaxf(s[0][r], s[1][r]);
    }
#pragma unroll
    for (int r = 0; r < 4; ++r) {
#pragma unroll
      for (int x = 1; x < 16; x <<= 1)
        tm[r] = fmaxf(tm[r], __shfl_xor(tm[r], x));
    }
    // online softmax update
    float alpha[4], rs[4];
#pragma unroll
    for (int r = 0; r < 4; ++r) {
      float mn = fmaxf(mrow[r], tm[r]);
      alpha[r] = __expf(mrow[r] - mn);
      mrow[r] = mn;
      float p0 = __expf(s[0][r] - mn);
      float p1 = __expf(s[1][r] - mn);
      s[0][r] = p0; s[1][r] = p1;
      rs[r] = p0 + p1;
    }
#pragma unroll
    for (int r = 0; r < 4; ++r) {
#pragma unroll
      for (int x = 1; x < 16; x <<= 1)
        rs[r] += __shfl_xor(rs[r], x);
      lsum[r] = lsum[r] * alpha[r] + rs[r];
    }
#pragma unroll
    for (int nt = 0; nt < 4; ++nt)
#pragma unroll
      for (int r = 0; r < 4; ++r) o[nt][r] *= alpha[r];
    // P -> LDS (bf16), then read back as A fragment
#pragma unroll
    for (int r = 0; r < 4; ++r) {
      plds[w][lg * 4 + r][lrow]      = f2bf(s[0][r]);
      plds[w][lg * 4 + r][16 + lrow] = f2bf(s[1][r]);
    }
    short8 pa = *(const short8*)&plds[w][lrow][lg * 8];
#pragma unroll
    for (int nt = 0; nt < 4; ++nt) {
      const ushort_t* vbase =
          vt + (size_t)(bh * DH_ + nt * 16 + lrow) * T_ + kv0 + lg * 8;
      short8 bvv = *(const short8*)(vbase);
      o[nt] = mfma16(pa, bvv, o[nt]);
    }
  }
  // normalize + store bf16 ctx
#pragma unroll
  for (int nt = 0; nt < 4; ++nt) {
#pragma unroll
    for (int r = 0; r < 4; ++r) {
      int row = qr0 + lg * 4 + r;
      ctx[(size_t)(b * T_ + row) * D_ + hh * DH_ + nt * 16 + lrow] =
          f2bf(o[nt][r] / lsum[r]);
    }
  }
}

extern "C" void kernel_launch(void* const* d_in, const int* in_sizes, int n_in,
                              void* d_out, int out_size, void* d_ws, size_t ws_size,
                              hipStream_t stream) {
  const float* x    = (const float*)d_in[0];
  // d_in[1] = mask (causal, known analytically -> unused)
  const float* Wqkv = (const float*)d_in[2];
  const float* Wo   = (const float*)d_in[3];
  float* out = (float*)d_out;

  char* ws = (char*)d_ws;
  ushort_t* xb    = (ushort_t*)(ws);                    //  8 MiB [4096][1024]
  ushort_t* wqkvT = (ushort_t*)(ws + (8u  << 20));      //  6 MiB [3072][1024]
  ushort_t* woT   = (ushort_t*)(ws + (14u << 20));      //  2 MiB [1024][1024]
  ushort_t* qkvb  = (ushort_t*)(ws + (16u << 20));      // 24 MiB [4096][3072]
  ushort_t* vtb   = (ushort_t*)(ws + (40u << 20));      //  8 MiB [32][64][2048]
  ushort_t* ctxb  = (ushort_t*)(ws + (48u << 20));      //  8 MiB [4096][1024]

  dim3 tb(32, 8);
  k_cvt<<<(B_ * T_ * D_) / 4 / 256, 256, 0, stream>>>(x, xb, (B_ * T_ * D_) / 4);
  k_tcvt<<<dim3(96, 32), tb, 0, stream>>>(Wqkv, wqkvT, 1024, 3072);
  k_tcvt<<<dim3(32, 32), tb, 0, stream>>>(Wo, woT, 1024, 1024);
  k_gemm_bt<0><<<dim3(24, 32), 256, 0, stream>>>(xb, wqkvT, qkvb, 4096, 3072, 1024);
  k_tv<<<dim3(64, 2, 32), tb, 0, stream>>>(qkvb, vtb);
  k_attn<<<dim3(32, 32), 256, 0, stream>>>(qkvb, vtb, ctxb);
  k_gemm_bt<1><<<dim3(8, 32), 256, 0, stream>>>(ctxb, woT, out, 4096, 1024, 1024);
}